// Round 6
// baseline (178.351 us; speedup 1.0000x reference)
//
#include <hip/hip_runtime.h>

// NonMaxSuppression (Canny thinning), H=W=4096, fp32.
//
// R5: copy-like streaming shape. Each thread handles 8 quads (4px) at a
// 512-row stride, software-pipelined double buffer: next tile's loads
// (3 mag rows + orient + edge-lane halo patches) issue before current tile's
// compute, keeping loads in flight across compute (vmcnt(N>0) waits instead
// of full drains). Plain loads (L3-friendly), nontemporal stores.

constexpr int H = 4096;
constexpr int W = 4096;
constexpr int T = 8;          // tiles (iterations) per thread
constexpr int ROWSTEP = 512;  // rows advanced per iteration

typedef float v4f __attribute__((ext_vector_type(4)));

struct Tile {
    v4f u, c, d, o;                       // rows y-1, y, y+1 (clamped), orient
    float lfu, lfc, lfd, rtu, rtc, rtd;   // lane-0 / lane-63 column halo
    float mtop, mbot;                     // row validity masks
};

__device__ __forceinline__ Tile load_tile(const float* __restrict__ mag,
                                          const float* __restrict__ orient,
                                          long base, int y, int x0, int lane)
{
    Tile t;
    const long uo = (y > 0)     ? -(long)W : 0;   // clamped row offsets:
    const long dn = (y < H - 1) ?  (long)W : 0;   // always a valid address
    t.c = *reinterpret_cast<const v4f*>(mag + base);
    t.u = *reinterpret_cast<const v4f*>(mag + base + uo);
    t.d = *reinterpret_cast<const v4f*>(mag + base + dn);
    t.o = *reinterpret_cast<const v4f*>(orient + base);
    t.mtop = (y > 0)     ? 1.f : 0.f;
    t.mbot = (y < H - 1) ? 1.f : 0.f;
    t.lfu = t.lfc = t.lfd = 0.f;
    t.rtu = t.rtc = t.rtd = 0.f;
    if (lane == 0 && x0 > 0) {
        t.lfc = mag[base - 1];
        t.lfu = mag[base + uo - 1];
        t.lfd = mag[base + dn - 1];
    }
    if (lane == 63 && x0 + 4 < W) {
        t.rtc = mag[base + 4];
        t.rtu = mag[base + uo + 4];
        t.rtd = mag[base + dn + 4];
    }
    return t;
}

// NMS over 4 pixels. u6/c6/d6 = 6-wide (x0-1..x0+4) slices of rows y-1,y,y+1.
// Direction table (dy,dx) by c:
// 0:(0,1) 1:(1,1) 2:(1,0) 3:(1,-1) 4:(0,-1) 5:(-1,-1) 6:(-1,0) 7:(-1,1)
__device__ __forceinline__ v4f nms_row(const float u6[6], const float c6[6],
                                       const float d6[6], v4f m4, v4f o4,
                                       const float b[8])
{
    v4f res;
    const float m[4] = {m4.x, m4.y, m4.z, m4.w};
    const float o[4] = {o4.x, o4.y, o4.z, o4.w};
    float r[4];
    #pragma unroll
    for (int k = 0; k < 4; ++k) {
        // orient is an exact multiple of 45 in [0,315]; mul+0.5+trunc
        // absorbs the 1-ulp reciprocal error. c in [0,7].
        const int c = (int)(o[k] * 0.0222222222f + 0.5f);
        const bool b0 = (c & 1), b1 = (c & 2), b2 = (c & 4);

        // t_i = n_i - bias_i  (pos = m - t[c], neg = m - t[c^4])
        const float t0 = c6[k + 2] - b[0];
        const float t1 = d6[k + 2] - b[1];
        const float t2 = d6[k + 1] - b[2];
        const float t3 = d6[k]     - b[3];
        const float t4 = c6[k]     - b[4];
        const float t5 = u6[k]     - b[5];
        const float t6 = u6[k + 1] - b[6];
        const float t7 = u6[k + 2] - b[7];

        // 3-level cndmask tree; levels 1-2 shared, level 3 flips on bit2
        const float s01 = b0 ? t1 : t0;
        const float s23 = b0 ? t3 : t2;
        const float s45 = b0 ? t5 : t4;
        const float s67 = b0 ? t7 : t6;
        const float lo  = b1 ? s23 : s01;
        const float hi  = b1 ? s67 : s45;
        const float tp  = b2 ? hi : lo;     // t[c]
        const float tn  = b2 ? lo : hi;     // t[c^4]

        // min(m-tp, m-tn) > 0  <=>  m > max(tp, tn)
        r[k] = (m[k] > fmaxf(tp, tn)) ? m[k] : 0.0f;
    }
    res.x = r[0]; res.y = r[1]; res.z = r[2]; res.w = r[3];
    return res;
}

__device__ __forceinline__ void process(const Tile& t, const float b[8],
                                        float* __restrict__ out, long base,
                                        int lane)
{
    const v4f u = t.u * t.mtop;
    const v4f d = t.d * t.mbot;
    float lu = __shfl_up(u.w, 1), lc = __shfl_up(t.c.w, 1), ld2 = __shfl_up(d.w, 1);
    float ru = __shfl_down(u.x, 1), rc = __shfl_down(t.c.x, 1), rd = __shfl_down(d.x, 1);
    if (lane == 0)  { lu = t.lfu * t.mtop; lc = t.lfc; ld2 = t.lfd * t.mbot; }
    if (lane == 63) { ru = t.rtu * t.mtop; rc = t.rtc; rd  = t.rtd * t.mbot; }

    const float u6[6] = {lu,  u.x,   u.y,   u.z,   u.w,   ru};
    const float c6[6] = {lc,  t.c.x, t.c.y, t.c.z, t.c.w, rc};
    const float d6[6] = {ld2, d.x,   d.y,   d.z,   d.w,   rd};

    const v4f res = nms_row(u6, c6, d6, t.c, t.o, b);
    __builtin_nontemporal_store(res, reinterpret_cast<v4f*>(out + base));
}

__global__ __launch_bounds__(256) void nms_kernel(
    const float* __restrict__ mag,
    const float* __restrict__ orient,
    const float* __restrict__ bias,
    float* __restrict__ out)
{
    const int tid  = blockIdx.x * 256 + threadIdx.x;   // [0, 524288)
    const int lane = threadIdx.x & 63;
    const int y0   = tid >> 10;                        // [0, 512)
    const int x0   = (tid & 1023) << 2;
    const long base0 = ((long)y0 << 12) + x0;
    const long bstep = (long)ROWSTEP * W;              // elements per iteration

    float b[8];
    #pragma unroll
    for (int i = 0; i < 8; ++i) b[i] = bias[i];

    // software pipeline: load(it+1) issued before process(it)
    Tile cur = load_tile(mag, orient, base0, y0, x0, lane);
    long pbase = base0;
    for (int it = 1; it < T; ++it) {
        const long nbase = base0 + (long)it * bstep;
        Tile nxt = load_tile(mag, orient, nbase, y0 + it * ROWSTEP, x0, lane);
        process(cur, b, out, pbase, lane);
        cur = nxt;
        pbase = nbase;
    }
    process(cur, b, out, pbase, lane);
}

extern "C" void kernel_launch(void* const* d_in, const int* in_sizes, int n_in,
                              void* d_out, int out_size, void* d_ws, size_t ws_size,
                              hipStream_t stream) {
    const float* mag    = (const float*)d_in[0];   // [1,1,H,W]
    const float* orient = (const float*)d_in[1];   // [1,1,H,W]
    // d_in[2] = weight [8,1,3,3] -- fixed directional filters, hardcoded
    const float* bias   = (const float*)d_in[3];   // [8]
    float* out = (float*)d_out;                    // [1,1,H,W]

    const int total_threads = (H / ROWSTEP == T) ? (H * W / 4 / T) : (H * W / 4 / T);
    dim3 block(256);
    dim3 grid(total_threads / 256);                // 2048 blocks
    hipLaunchKernelGGL(nms_kernel, grid, block, 0, stream,
                       mag, orient, bias, out);
}

// Round 7
// 177.377 us; speedup vs baseline: 1.0055x; 1.0055x over previous
//
#include <hip/hip_runtime.h>

// NonMaxSuppression (Canny thinning), H=W=4096, fp32.
//
// R6: streaming register pipeline. Block = 1024-px-wide x 8-row strip;
// each thread owns a 4-px column and slides down, keeping mag rows
// (y-1,y,y+1) in registers. Per row: issue 1 mag load (2 ahead) + 1 orient
// load (1 ahead) + NT store -> loads continuously in flight (copy-like).
// Pair-max trick: min(pos,neg)>0 <=> m > max(q[c],q[c^4]) = M[c&3],
// M[j]=max(n_j-b_j, n_{j+4}-b_{j+4}) -> 3-cndmask select, bit2 unused.

constexpr int H = 4096;
constexpr int W = 4096;
constexpr int RPB = 8;              // output rows per block

typedef float v4f __attribute__((ext_vector_type(4)));

struct RowRaw { v4f m; float pl, pr; };   // pl/pr valid on lanes 0/63 only
struct Row    { v4f m; float lf, rt; };   // resolved: halo via shuffle

__device__ __forceinline__ RowRaw load_row(const float* __restrict__ mag,
                                           int r, long xb,
                                           bool has_l, bool has_r, int lane)
{
    const int rc = min(max(r, 0), H - 1);        // address-valid clamp
    const long a = (long)rc * W + xb;
    RowRaw t;
    t.m = *reinterpret_cast<const v4f*>(mag + a);
    t.pl = 0.f; t.pr = 0.f;
    if (lane == 0  && has_l) t.pl = mag[a - 1];
    if (lane == 63 && has_r) t.pr = mag[a + 4];
    return t;
}

__device__ __forceinline__ Row resolve(const RowRaw& t, int r, int lane)
{
    const float mask = (r >= 0 && r < H) ? 1.f : 0.f;  // wave-uniform
    Row o;
    o.m = t.m * mask;
    float lf = __shfl_up(o.m.w, 1);
    float rt = __shfl_down(o.m.x, 1);
    if (lane == 0)  lf = t.pl * mask;
    if (lane == 63) rt = t.pr * mask;
    o.lf = lf; o.rt = rt;
    return o;
}

// NMS for 4 px. Rows rA (y-1), rB (y), rC (y+1). Direction (dy,dx) by c:
// 0:(0,1) 1:(1,1) 2:(1,0) 3:(1,-1) 4:(0,-1) 5:(-1,-1) 6:(-1,0) 7:(-1,1)
__device__ __forceinline__ v4f nms_quad(const Row& rA, const Row& rB,
                                        const Row& rC, v4f o4,
                                        const float b[8])
{
    const float u6[6] = {rA.lf, rA.m.x, rA.m.y, rA.m.z, rA.m.w, rA.rt};
    const float c6[6] = {rB.lf, rB.m.x, rB.m.y, rB.m.z, rB.m.w, rB.rt};
    const float d6[6] = {rC.lf, rC.m.x, rC.m.y, rC.m.z, rC.m.w, rC.rt};
    const float m[4]  = {rB.m.x, rB.m.y, rB.m.z, rB.m.w};
    const float o[4]  = {o4.x, o4.y, o4.z, o4.w};

    float r[4];
    #pragma unroll
    for (int k = 0; k < 4; ++k) {
        // orient is an exact multiple of 45 in [0,315]; mul+0.5+trunc
        // absorbs the 1-ulp reciprocal error. Only c&3 is needed.
        const int c = (int)(o[k] * 0.0222222222f + 0.5f);
        const bool b0 = (c & 1), b1 = (c & 2);

        // M[j] = max(n_j - bias_j, n_{j+4} - bias_{j+4}), j = c & 3
        const float M0 = fmaxf(c6[k + 2] - b[0], c6[k]     - b[4]);
        const float M1 = fmaxf(d6[k + 2] - b[1], u6[k]     - b[5]);
        const float M2 = fmaxf(d6[k + 1] - b[2], u6[k + 1] - b[6]);
        const float M3 = fmaxf(d6[k]     - b[3], u6[k + 2] - b[7]);

        const float m01 = b0 ? M1 : M0;
        const float m23 = b0 ? M3 : M2;
        const float Mj  = b1 ? m23 : m01;

        // min(pos, neg) > 0  <=>  m > M[c&3]
        r[k] = (m[k] > Mj) ? m[k] : 0.0f;
    }
    v4f res; res.x = r[0]; res.y = r[1]; res.z = r[2]; res.w = r[3];
    return res;
}

__global__ __launch_bounds__(256) void nms_kernel(
    const float* __restrict__ mag,
    const float* __restrict__ orient,
    const float* __restrict__ bias,
    float* __restrict__ out)
{
    const int tx   = threadIdx.x;
    const int lane = tx & 63;
    const int band = blockIdx.x & 3;         // 4 bands of 1024 px
    const int seg  = blockIdx.x >> 2;        // 512 row-segments of 8 rows
    const int x0   = band * 1024 + tx * 4;
    const long xb  = x0;
    const bool has_l = (x0 > 0);
    const bool has_r = (x0 + 4 < W);
    const int r0   = seg * RPB;

    float b[8];
    #pragma unroll
    for (int i = 0; i < 8; ++i) b[i] = bias[i];

    // prologue: rows r0-1, r0 resolved; r0+1 raw; orient r0 loaded
    RowRaw a_raw = load_row(mag, r0 - 1, xb, has_l, has_r, lane);
    RowRaw b_raw = load_row(mag, r0,     xb, has_l, has_r, lane);
    RowRaw c_raw = load_row(mag, r0 + 1, xb, has_l, has_r, lane);
    v4f o_cur = *reinterpret_cast<const v4f*>(orient + (long)r0 * W + xb);
    Row rA = resolve(a_raw, r0 - 1, lane);
    Row rB = resolve(b_raw, r0, lane);

    #pragma unroll
    for (int i = 0; i < RPB; ++i) {
        const int r = r0 + i;
        // issue next loads first: mag row r+2 (2 ahead), orient r+1 (1 ahead)
        RowRaw d_raw = load_row(mag, r + 2, xb, has_l, has_r, lane);
        const int ro = min(r + 1, H - 1);    // address-valid; unused on last
        v4f o_nxt = *reinterpret_cast<const v4f*>(orient + (long)ro * W + xb);

        // resolve row r+1 (its load was issued 2 iterations ago)
        Row rC = resolve(c_raw, r + 1, lane);

        const v4f res = nms_quad(rA, rB, rC, o_cur, b);
        __builtin_nontemporal_store(
            res, reinterpret_cast<v4f*>(out + (long)r * W + xb));

        rA = rB; rB = rC; c_raw = d_raw; o_cur = o_nxt;
    }
}

extern "C" void kernel_launch(void* const* d_in, const int* in_sizes, int n_in,
                              void* d_out, int out_size, void* d_ws, size_t ws_size,
                              hipStream_t stream) {
    const float* mag    = (const float*)d_in[0];   // [1,1,H,W]
    const float* orient = (const float*)d_in[1];   // [1,1,H,W]
    // d_in[2] = weight [8,1,3,3] -- fixed directional filters, hardcoded
    const float* bias   = (const float*)d_in[3];   // [8]
    float* out = (float*)d_out;                    // [1,1,H,W]

    dim3 block(256);
    dim3 grid((H / RPB) * 4);                      // 2048 blocks
    hipLaunchKernelGGL(nms_kernel, grid, block, 0, stream,
                       mag, orient, bias, out);
}